// Round 8
// baseline (521.999 us; speedup 1.0000x reference)
//
#include <hip/hip_runtime.h>

#define T_STEPS 100
#define NTRAJ   8192
#define MBLK    16
#define W3_TILES 45
#define W3_BYTES (W3_TILES * 1024)          // 46080: G3 weights (tiles 30..74)
#define ACT_BYTES 26624                     // activation buffers + sYO f32
#define LDS_TOTAL (W3_BYTES + ACT_BYTES)    // 72704 -> 2 blocks/CU = 145408 <= 163840

typedef __attribute__((ext_vector_type(8))) _Float16 f16x8;
typedef __attribute__((ext_vector_type(4))) float    f32x4;

#define MFMA16(a, b, c) __builtin_amdgcn_mfma_f32_16x16x32_f16((a), (b), (c), 0, 0, 0)

// XOR swizzle on element index within a row (2B elems; XOR elem bits 3..5)
#define SWZ(row, col) ((col) ^ (((row) & 7) << 3))

__device__ __forceinline__ float fast_tanh(float x) {
    float e = __expf(2.f * x);
    return 1.f - 2.f * __builtin_amdgcn_rcpf(1.f + e);
}
__device__ __forceinline__ float fast_sigmoid(float x) {
    float e = __expf(-x);
    return __builtin_amdgcn_rcpf(1.f + e);
}

// ---------------------------------------------------------------------------
// Weight packing (unchanged): B-fragment tile order, 144 tiles of 512 f16.
//   [0,14) G1 | [14,30) G2 | [30,75) G3 | [75,107) G4 | [107,128) G5 | [128,144) G6
// ---------------------------------------------------------------------------
__global__ void pack_kernel(const float* __restrict__ Wo1, const float* __restrict__ Wo2,
                            const float* __restrict__ Wz1, const float* __restrict__ Wz2,
                            const float* __restrict__ Wr1, const float* __restrict__ Wr2,
                            const float* __restrict__ Wh1, const float* __restrict__ Wh2,
                            _Float16* __restrict__ P)
{
    int idx = blockIdx.x * 256 + threadIdx.x;
    if (idx >= 144 * 512) return;
    int tile = idx >> 9;
    int r    = idx & 511;
    int lane = r >> 3, j = r & 7;
    int krel = ((lane >> 4) << 3) + j;   // 0..31
    int c16  = lane & 15;
    float val = 0.f;

    if (tile < 14) {                       // ODE L1
        int t = tile, nt = t >> 1, kt = t & 1;
        int k = kt * 32 + krel, n = nt * 16 + c16;
        if (k < 64 && n < 100) val = Wo1[k * 100 + n];
    } else if (tile < 30) {                // ODE L2
        int t = tile - 14, nt = t >> 2, kt = t & 3;
        int k = kt * 32 + krel, n = nt * 16 + c16;
        if (k < 100) val = Wo2[k * 64 + n];
    } else if (tile < 75) {                // ZR L1
        int t = tile - 30, nt = t / 3, kt = t % 3;
        int k = kt * 32 + krel;            // K = 96 exact
        if (nt < 7)      { int n = nt * 16 + c16;        if (n < 100) val = Wz1[k * 100 + n]; }
        else if (nt >= 8){ int n = (nt - 8) * 16 + c16;  if (n < 100) val = Wr1[k * 100 + n]; }
    } else if (tile < 107) {               // ZR L2
        int t = tile - 75, gate = t >> 4, rem = t & 15, nt = rem >> 2, kt = rem & 3;
        int k = kt * 32 + krel, n = nt * 16 + c16;
        const float* W = gate ? Wr2 : Wz2;
        if (k < 100) val = W[k * 64 + n];
    } else if (tile < 128) {               // H L1
        int t = tile - 107, nt = t / 3, kt = t % 3;
        int k = kt * 32 + krel, n = nt * 16 + c16;
        if (n < 100) val = Wh1[k * 100 + n];
    } else {                               // H L2
        int t = tile - 128, nt = t >> 2, kt = t & 3;
        int k = kt * 32 + krel, n = nt * 16 + c16;
        if (k < 100) val = Wh2[k * 64 + n];
    }
    P[idx] = (_Float16)val;
}

__device__ __forceinline__ f16x8 ldsA(const _Float16* buf, int stride, int row, int kcol) {
    return *(const f16x8*)(buf + row * stride + SWZ(row, kcol));
}

// ---------------------------------------------------------------------------
// Main kernel. Block = 16 trajectories, 512 threads = 8 waves, grid = 512
// -> 4096 waves total; with <=128 total regs/wave and 72.7 KB LDS, 2 blocks
// co-reside per CU = 16 waves/CU (2x the round-1..6 residency).
// NO register fragment preloads (rounds 1-6 lesson: preloads push the unified
// VGPR+AGPR footprint past the 128 granule -> stuck at 2 waves/SIMD).
// G3 weights (45KB, biggest per-step consumer) live in LDS; all other phases
// stream B-frags from L2 (~20 TB/s aggregate < 34.5 TB/s ceiling).
// Biases folded into MFMA C-operand init.
// ---------------------------------------------------------------------------
__global__ __launch_bounds__(512, 2) void odernn_kernel(
    const float* __restrict__ data, const float* __restrict__ ts,
    const float* __restrict__ prior,
    const float* __restrict__ bo1, const float* __restrict__ bo2,
    const float* __restrict__ bz1, const float* __restrict__ bz2,
    const float* __restrict__ br1, const float* __restrict__ br2,
    const float* __restrict__ bh1, const float* __restrict__ bh2,
    const _Float16* __restrict__ P, float* __restrict__ out)
{
    extern __shared__ __align__(16) char smem[];
    _Float16* W3  = (_Float16*)smem;                  // 45 tiles, local idx = (bt*3+kt)
    _Float16* base = (_Float16*)(smem + W3_BYTES);
    _Float16* sYb = base;                 // [16][64]  y (f16), G1 A input
    _Float16* sYX = base + 1024;          // [16][128] [yode | x]
    _Float16* sRX = base + 3072;          // [16][128] [rg*yode | x]
    _Float16* sH1 = base + 5120;          // [16][128] hidden (ODE L1 / H L1)
    _Float16* sZR = base + 7168;          // [16][256] [zh(112)+pad | rh(112)+pad]
    float*    sYO = (float*)(base + 11264); // [16][64] yode f32 for r-gate waves

    const int tid  = threadIdx.x;
    const int lane = tid & 63;
    const int wv   = tid >> 6;            // 0..7
    const int c16  = lane & 15;
    const int g4   = lane >> 4;
    const int m0   = blockIdx.x * MBLK;
    const f16x8* Pt  = (const f16x8*)P;
    const f16x8* Wv3 = (const f16x8*)W3;

    const int colw = (wv & 3) * 16 + c16;   // state column (waves 0-3) / r-tile col (4-7)

    // ---- stage G3 weights (tiles 30..74) into LDS, linear/conflict-free ----
    for (int idx = tid; idx < W3_TILES * 64; idx += 512)
        ((f16x8*)W3)[idx] = Pt[30 * 64 + idx];

    // ---- biases (step-invariant per lane) ----
    float b_o1 = 0.f, b_h1 = 0.f, b_zr0 = 0.f, b_zr1 = 0.f;
    if (wv < 7) {
        int c = wv * 16 + c16;
        if (c < 100) { b_o1 = bo1[c]; b_h1 = bh1[c]; }
    }
    {   // G3 tile A: t = wv (z if wv<7, r if wv==7); tile B: t = wv+8 (r), wv<6
        if (wv < 7) { int c = wv * 16 + c16; if (c < 100) b_zr0 = bz1[c]; }
        else        { b_zr0 = br1[c16]; }
        if (wv < 6) { int bc = (wv + 1) * 16 + c16; if (bc < 100) b_zr1 = br1[bc]; }
    }
    float b_o2 = 0.f, b_h2 = 0.f;
    if (wv < 4) { b_o2 = bo2[colw]; b_h2 = bh2[colw]; }
    const float b_g4 = (wv < 4) ? bz2[colw] : br2[colw];

    // ---- init: y state in regs (waves 0-3 cover all 64 cols), pads ----
    float y[4] = {0.f, 0.f, 0.f, 0.f};
    if (wv < 4) {
        #pragma unroll
        for (int r = 0; r < 4; ++r) {
            int row = g4 * 4 + r;
            y[r] = prior[(size_t)(m0 + row) * 64 + colw];
            sYb[row * 64 + SWZ(row, colw)] = (_Float16)y[r];
        }
    }
    if (tid < 256) {
        int row = tid >> 4, col = 112 + (tid & 15);
        sH1[row * 128 + SWZ(row, col)] = (_Float16)0.f;
    }
    {
        int row = tid >> 5, cc = tid & 31;
        int col = (cc < 16) ? (112 + cc) : (224 + cc);
        sZR[row * 256 + SWZ(row, col)] = (_Float16)0.f;
    }
    __syncthreads();

    const float t0 = ts[0], t1 = ts[1];

    // x element owned by this thread (row = tid>>5, c = tid&31), t = s+1
    const int xrow = tid >> 5, xc = tid & 31;
    const float* xptr = data + (size_t)(m0 + xrow) * (T_STEPS * 32) + 32 + xc;
    const int xsw = xrow * 128 + SWZ(xrow, 64 + xc);

    #pragma unroll 1
    for (int s = 0; s < T_STEPS - 1; ++s) {
        const float dt = (s == 0) ? (t1 - t0) : (ts[s - 1] - ts[s]);
        float xv = *xptr; xptr += 32;

        // ---- G1: H1 = tanh(y @ Wo1 + bo1) — wave w<7 owns tile nt=w ----
        if (wv < 7) {
            f16x8 w0 = Pt[(wv * 2 + 0) * 64 + lane];
            f16x8 w1 = Pt[(wv * 2 + 1) * 64 + lane];
            f16x8 a0 = ldsA(sYb, 64, c16, (g4 << 3));
            f16x8 a1 = ldsA(sYb, 64, c16, 32 + (g4 << 3));
            f32x4 acc0 = {b_o1, b_o1, b_o1, b_o1};
            f32x4 z4 = {0.f, 0.f, 0.f, 0.f};
            acc0 = MFMA16(a0, w0, acc0);
            f32x4 acc1 = MFMA16(a1, w1, z4);
            int col = wv * 16 + c16;
            #pragma unroll
            for (int r = 0; r < 4; ++r) {
                int row = g4 * 4 + r;
                sH1[row * 128 + SWZ(row, col)] = (_Float16)fast_tanh(acc0[r] + acc1[r]);
            }
        }
        // stage x into both concat buffers (one elem per thread)
        {
            _Float16 xh = (_Float16)xv;
            sYX[xsw] = xh; sRX[xsw] = xh;
        }
        __syncthreads();

        // ---- G2: yode = y + dt*(H1 @ Wo2 + bo2) — waves 0-3 ----
        float yo[4] = {0.f, 0.f, 0.f, 0.f};
        if (wv < 4) {
            f16x8 w0 = Pt[(14 + wv * 4 + 0) * 64 + lane];
            f16x8 w1 = Pt[(14 + wv * 4 + 1) * 64 + lane];
            f16x8 w2 = Pt[(14 + wv * 4 + 2) * 64 + lane];
            f16x8 w3 = Pt[(14 + wv * 4 + 3) * 64 + lane];
            f32x4 acc0 = {b_o2, b_o2, b_o2, b_o2};
            f32x4 z4 = {0.f, 0.f, 0.f, 0.f};
            acc0 = MFMA16(ldsA(sH1, 128, c16, 0 * 32 + (g4 << 3)), w0, acc0);
            f32x4 acc1 = MFMA16(ldsA(sH1, 128, c16, 1 * 32 + (g4 << 3)), w1, z4);
            acc0 = MFMA16(ldsA(sH1, 128, c16, 2 * 32 + (g4 << 3)), w2, acc0);
            acc1 = MFMA16(ldsA(sH1, 128, c16, 3 * 32 + (g4 << 3)), w3, acc1);
            #pragma unroll
            for (int r = 0; r < 4; ++r) {
                int row = g4 * 4 + r;
                yo[r] = y[r] + dt * (acc0[r] + acc1[r]);
                sYO[row * 64 + colw] = yo[r];
                sYX[row * 128 + SWZ(row, colw)] = (_Float16)yo[r];
            }
        }
        __syncthreads();

        // ---- G3: zr-hidden = tanh([yode|x] @ W{z,r}1 + b) — LDS weights ----
        {
            f16x8 a0 = ldsA(sYX, 128, c16, 0 * 32 + (g4 << 3));
            f16x8 a1 = ldsA(sYX, 128, c16, 1 * 32 + (g4 << 3));
            f16x8 a2 = ldsA(sYX, 128, c16, 2 * 32 + (g4 << 3));
            f32x4 z4 = {0.f, 0.f, 0.f, 0.f};
            {   // tile A: t = wv
                int lt = ((wv < 7) ? wv : wv + 1) * 3;
                f32x4 acc0 = {b_zr0, b_zr0, b_zr0, b_zr0};
                acc0 = MFMA16(a0, Wv3[(lt + 0) * 64 + lane], acc0);
                f32x4 acc1 = MFMA16(a1, Wv3[(lt + 1) * 64 + lane], z4);
                acc0 = MFMA16(a2, Wv3[(lt + 2) * 64 + lane], acc0);
                int col = ((wv < 7) ? wv : wv + 1) * 16 + c16;
                #pragma unroll
                for (int r = 0; r < 4; ++r) {
                    int row = g4 * 4 + r;
                    sZR[row * 256 + SWZ(row, col)] = (_Float16)fast_tanh(acc0[r] + acc1[r]);
                }
            }
            if (wv < 6) {   // tile B: always r-gate, bt = wv+9
                int lt = (wv + 9) * 3;
                f32x4 acc0 = {b_zr1, b_zr1, b_zr1, b_zr1};
                acc0 = MFMA16(a0, Wv3[(lt + 0) * 64 + lane], acc0);
                f32x4 acc1 = MFMA16(a1, Wv3[(lt + 1) * 64 + lane], z4);
                acc0 = MFMA16(a2, Wv3[(lt + 2) * 64 + lane], acc0);
                int col = (wv + 9) * 16 + c16;
                #pragma unroll
                for (int r = 0; r < 4; ++r) {
                    int row = g4 * 4 + r;
                    sZR[row * 256 + SWZ(row, col)] = (_Float16)fast_tanh(acc0[r] + acc1[r]);
                }
            }
        }
        __syncthreads();

        // ---- G4: z-gate (waves 0-3 -> regs) ; r-gate (waves 4-7 -> sRX) ----
        float zg[4] = {0.f, 0.f, 0.f, 0.f};
        {
            int half = (wv < 4) ? 0 : 128;
            int fb = (wv < 4) ? (75 + wv * 4) : (91 + (wv - 4) * 4);
            f16x8 w0 = Pt[(fb + 0) * 64 + lane];
            f16x8 w1 = Pt[(fb + 1) * 64 + lane];
            f16x8 w2 = Pt[(fb + 2) * 64 + lane];
            f16x8 w3 = Pt[(fb + 3) * 64 + lane];
            f32x4 acc0 = {b_g4, b_g4, b_g4, b_g4};
            f32x4 z4 = {0.f, 0.f, 0.f, 0.f};
            acc0 = MFMA16(ldsA(sZR, 256, c16, half + 0 * 32 + (g4 << 3)), w0, acc0);
            f32x4 acc1 = MFMA16(ldsA(sZR, 256, c16, half + 1 * 32 + (g4 << 3)), w1, z4);
            acc0 = MFMA16(ldsA(sZR, 256, c16, half + 2 * 32 + (g4 << 3)), w2, acc0);
            acc1 = MFMA16(ldsA(sZR, 256, c16, half + 3 * 32 + (g4 << 3)), w3, acc1);
            if (wv < 4) {
                #pragma unroll
                for (int r = 0; r < 4; ++r) zg[r] = fast_sigmoid(acc0[r] + acc1[r]);
            } else {
                #pragma unroll
                for (int r = 0; r < 4; ++r) {
                    int row = g4 * 4 + r;
                    float rv = fast_sigmoid(acc0[r] + acc1[r]) * sYO[row * 64 + colw];
                    sRX[row * 128 + SWZ(row, colw)] = (_Float16)rv;
                }
            }
        }
        __syncthreads();

        // ---- G5: H1 = tanh([rg*yode|x] @ Wh1 + bh1) — wave w<7 owns nt=w ----
        if (wv < 7) {
            f16x8 w0 = Pt[(107 + wv * 3 + 0) * 64 + lane];
            f16x8 w1 = Pt[(107 + wv * 3 + 1) * 64 + lane];
            f16x8 w2 = Pt[(107 + wv * 3 + 2) * 64 + lane];
            f16x8 a0 = ldsA(sRX, 128, c16, 0 * 32 + (g4 << 3));
            f16x8 a1 = ldsA(sRX, 128, c16, 1 * 32 + (g4 << 3));
            f16x8 a2 = ldsA(sRX, 128, c16, 2 * 32 + (g4 << 3));
            f32x4 acc0 = {b_h1, b_h1, b_h1, b_h1};
            f32x4 z4 = {0.f, 0.f, 0.f, 0.f};
            acc0 = MFMA16(a0, w0, acc0);
            f32x4 acc1 = MFMA16(a1, w1, z4);
            acc0 = MFMA16(a2, w2, acc0);
            int col = wv * 16 + c16;
            #pragma unroll
            for (int r = 0; r < 4; ++r) {
                int row = g4 * 4 + r;
                sH1[row * 128 + SWZ(row, col)] = (_Float16)fast_tanh(acc0[r] + acc1[r]);
            }
        }
        __syncthreads();

        // ---- G6: h = tanh(H1 @ Wh2 + bh2); y = (1-z)*h + z*yode — waves 0-3 ----
        if (wv < 4) {
            f16x8 w0 = Pt[(128 + wv * 4 + 0) * 64 + lane];
            f16x8 w1 = Pt[(128 + wv * 4 + 1) * 64 + lane];
            f16x8 w2 = Pt[(128 + wv * 4 + 2) * 64 + lane];
            f16x8 w3 = Pt[(128 + wv * 4 + 3) * 64 + lane];
            f32x4 acc0 = {b_h2, b_h2, b_h2, b_h2};
            f32x4 z4 = {0.f, 0.f, 0.f, 0.f};
            acc0 = MFMA16(ldsA(sH1, 128, c16, 0 * 32 + (g4 << 3)), w0, acc0);
            f32x4 acc1 = MFMA16(ldsA(sH1, 128, c16, 1 * 32 + (g4 << 3)), w1, z4);
            acc0 = MFMA16(ldsA(sH1, 128, c16, 2 * 32 + (g4 << 3)), w2, acc0);
            acc1 = MFMA16(ldsA(sH1, 128, c16, 3 * 32 + (g4 << 3)), w3, acc1);
            #pragma unroll
            for (int r = 0; r < 4; ++r) {
                int row = g4 * 4 + r;
                float h = fast_tanh(acc0[r] + acc1[r]);
                y[r] = (1.f - zg[r]) * h + zg[r] * yo[r];
                sYb[row * 64 + SWZ(row, colw)] = (_Float16)y[r];
            }
        }
        __syncthreads();
    }

    if (wv < 4) {
        #pragma unroll
        for (int r = 0; r < 4; ++r) {
            int row = g4 * 4 + r;
            out[(size_t)(m0 + row) * 64 + colw] = y[r];
        }
    }
}

extern "C" void kernel_launch(void* const* d_in, const int* in_sizes, int n_in,
                              void* d_out, int out_size, void* d_ws, size_t ws_size,
                              hipStream_t stream) {
    const float* data = (const float*)d_in[0];
    const float* ts   = (const float*)d_in[1];
    const float* prior= (const float*)d_in[2];
    const float* Wo1 = (const float*)d_in[3];  const float* bo1 = (const float*)d_in[4];
    const float* Wo2 = (const float*)d_in[5];  const float* bo2 = (const float*)d_in[6];
    const float* Wz1 = (const float*)d_in[7];  const float* bz1 = (const float*)d_in[8];
    const float* Wz2 = (const float*)d_in[9];  const float* bz2 = (const float*)d_in[10];
    const float* Wr1 = (const float*)d_in[11]; const float* br1 = (const float*)d_in[12];
    const float* Wr2 = (const float*)d_in[13]; const float* br2 = (const float*)d_in[14];
    const float* Wh1 = (const float*)d_in[15]; const float* bh1 = (const float*)d_in[16];
    const float* Wh2 = (const float*)d_in[17]; const float* bh2 = (const float*)d_in[18];
    _Float16* P = (_Float16*)d_ws;
    float* out = (float*)d_out;

    // opt-in to >64KB dynamic LDS (immediate API, graph-capture safe)
    hipFuncSetAttribute((const void*)odernn_kernel,
                        hipFuncAttributeMaxDynamicSharedMemorySize, LDS_TOTAL);

    hipLaunchKernelGGL(pack_kernel, dim3((144 * 512 + 255) / 256), dim3(256), 0, stream,
                       Wo1, Wo2, Wz1, Wz2, Wr1, Wr2, Wh1, Wh2, P);
    hipLaunchKernelGGL(odernn_kernel, dim3(NTRAJ / MBLK), dim3(512), LDS_TOTAL, stream,
                       data, ts, prior, bo1, bo2, bz1, bz2, br1, br2, bh1, bh2, P, out);
}

// Round 9
// 382.417 us; speedup vs baseline: 1.3650x; 1.3650x over previous
//
#include <hip/hip_runtime.h>

#define T_STEPS 100
#define NTRAJ   8192
#define MBLK    32     // two 16-row tile groups per block
#define W_TILES 112
#define W_BYTES (W_TILES * 1024)            // 114688: G1/G3/G4/G5 weights
#define TILEBUF 22528                       // per-group activation buffers
#define LDS_TOTAL (W_BYTES + 2 * TILEBUF)   // 159744 <= 163840

typedef __attribute__((ext_vector_type(8))) _Float16 f16x8;
typedef __attribute__((ext_vector_type(4))) float    f32x4;

#define MFMA16(a, b, c) __builtin_amdgcn_mfma_f32_16x16x32_f16((a), (b), (c), 0, 0, 0)

// XOR swizzle on element index within a row (2B elems; XOR elem bits 3..5)
#define SWZ(row, col) ((col) ^ (((row) & 7) << 3))

__device__ __forceinline__ float fast_tanh(float x) {
    float e = __expf(2.f * x);
    return 1.f - 2.f * __builtin_amdgcn_rcpf(1.f + e);
}
__device__ __forceinline__ float fast_sigmoid(float x) {
    float e = __expf(-x);
    return __builtin_amdgcn_rcpf(1.f + e);
}

// ---------------------------------------------------------------------------
// Weight packing (unchanged): B-fragment tile order, 144 tiles of 512 f16.
//   [0,14) G1 | [14,30) G2 | [30,75) G3 | [75,107) G4 | [107,128) G5 | [128,144) G6
// ---------------------------------------------------------------------------
__global__ void pack_kernel(const float* __restrict__ Wo1, const float* __restrict__ Wo2,
                            const float* __restrict__ Wz1, const float* __restrict__ Wz2,
                            const float* __restrict__ Wr1, const float* __restrict__ Wr2,
                            const float* __restrict__ Wh1, const float* __restrict__ Wh2,
                            _Float16* __restrict__ P)
{
    int idx = blockIdx.x * 256 + threadIdx.x;
    if (idx >= 144 * 512) return;
    int tile = idx >> 9;
    int r    = idx & 511;
    int lane = r >> 3, j = r & 7;
    int krel = ((lane >> 4) << 3) + j;   // 0..31
    int c16  = lane & 15;
    float val = 0.f;

    if (tile < 14) {                       // ODE L1
        int t = tile, nt = t >> 1, kt = t & 1;
        int k = kt * 32 + krel, n = nt * 16 + c16;
        if (k < 64 && n < 100) val = Wo1[k * 100 + n];
    } else if (tile < 30) {                // ODE L2
        int t = tile - 14, nt = t >> 2, kt = t & 3;
        int k = kt * 32 + krel, n = nt * 16 + c16;
        if (k < 100) val = Wo2[k * 64 + n];
    } else if (tile < 75) {                // ZR L1
        int t = tile - 30, nt = t / 3, kt = t % 3;
        int k = kt * 32 + krel;            // K = 96 exact
        if (nt < 7)      { int n = nt * 16 + c16;        if (n < 100) val = Wz1[k * 100 + n]; }
        else if (nt >= 8){ int n = (nt - 8) * 16 + c16;  if (n < 100) val = Wr1[k * 100 + n]; }
    } else if (tile < 107) {               // ZR L2
        int t = tile - 75, gate = t >> 4, rem = t & 15, nt = rem >> 2, kt = rem & 3;
        int k = kt * 32 + krel, n = nt * 16 + c16;
        const float* W = gate ? Wr2 : Wz2;
        if (k < 100) val = W[k * 64 + n];
    } else if (tile < 128) {               // H L1
        int t = tile - 107, nt = t / 3, kt = t % 3;
        int k = kt * 32 + krel, n = nt * 16 + c16;
        if (n < 100) val = Wh1[k * 100 + n];
    } else {                               // H L2
        int t = tile - 128, nt = t >> 2, kt = t & 3;
        int k = kt * 32 + krel, n = nt * 16 + c16;
        if (k < 100) val = Wh2[k * 64 + n];
    }
    P[idx] = (_Float16)val;
}

__device__ __forceinline__ f16x8 ldsA(const _Float16* buf, int stride, int row, int kcol) {
    return *(const f16x8*)(buf + row * stride + SWZ(row, kcol));
}

// ---------------------------------------------------------------------------
// Main kernel = R6 (351us best) + PHASE STAGGER: group 1 runs one phase
// behind group 0, so the two waves sharing each SIMD (wave i / wave i+4)
// are always in DIFFERENT phases -> stalls decorrelate, MFMA of one group
// overlaps VALU of the other. Barrier count unchanged. Biases folded into
// MFMA C-operand init. Occupancy stays 8 waves/CU (register/LDS-pinned;
// accepted after rounds 2/4/5/7).
// ---------------------------------------------------------------------------
__global__ __launch_bounds__(512, 2) void odernn_kernel(
    const float* __restrict__ data, const float* __restrict__ ts,
    const float* __restrict__ prior,
    const float* __restrict__ bo1, const float* __restrict__ bo2,
    const float* __restrict__ bz1, const float* __restrict__ bz2,
    const float* __restrict__ br1, const float* __restrict__ br2,
    const float* __restrict__ bh1, const float* __restrict__ bh2,
    const _Float16* __restrict__ P, float* __restrict__ out)
{
    extern __shared__ __align__(16) char smem[];
    _Float16* W = (_Float16*)smem;        // 112 tiles: G1[0,14) G3[14,59) G4[59,91) G5[91,112)

    const int tid  = threadIdx.x;
    const int lane = tid & 63;
    const int wv   = tid >> 6;            // 0..7
    const int tg   = wv >> 2;             // tile group 0/1
    const int wq   = wv & 3;              // wave-in-group
    const int c16  = lane & 15;
    const int g4   = lane >> 4;
    const int m0b  = blockIdx.x * MBLK;
    const int m0   = m0b + tg * 16;
    const int colw = wq * 16 + c16;
    const f16x8* Pt = (const f16x8*)P;
    const f16x8* Wv = (const f16x8*)W;

    _Float16* base = (_Float16*)(smem + W_BYTES + tg * TILEBUF);
    _Float16* sYb = base;                 // [16][64]
    _Float16* sYX = base + 1024;          // [16][128]
    _Float16* sRX = base + 3072;          // [16][128]
    _Float16* sH1 = base + 5120;          // [16][128]
    _Float16* sZR = base + 7168;          // [16][256]

    // ---- stage G1/G3/G4/G5 weights into LDS ----
    {
        f16x8* Wd = (f16x8*)W;
        #pragma unroll
        for (int it = 0; it < 14; ++it) {
            int idx = tid + it * 512;
            int ldst = idx >> 6, l = idx & 63;
            int srct = (ldst < 14) ? ldst : ldst + 16;   // skip G2 range
            Wd[idx] = Pt[srct * 64 + l];
        }
    }

    // ---- biases ----
    float b_o1[2], b_h1[2], b_zr[4];
    {
        int c0 = wq * 16 + c16, c1 = (wq + 4) * 16 + c16;
        b_o1[0] = (c0 < 100) ? bo1[c0] : 0.f;
        b_h1[0] = (c0 < 100) ? bh1[c0] : 0.f;
        b_o1[1] = (wq + 4 < 7 && c1 < 100) ? bo1[c1] : 0.f;
        b_h1[1] = (wq + 4 < 7 && c1 < 100) ? bh1[c1] : 0.f;
        #pragma unroll
        for (int q = 0; q < 4; ++q) {
            int i = wq + 4 * q;
            float v = 0.f;
            if (i < 14) {
                int bt = (i < 7) ? i : i + 1;
                int col = bt * 16 + c16;
                int bc = (i < 7) ? col : col - 128;
                if (bc < 100) v = (i < 7) ? bz1[bc] : br1[bc];
            }
            b_zr[q] = v;
        }
    }
    const float b_o2 = bo2[colw], b_z2 = bz2[colw], b_r2 = br2[colw], b_h2 = bh2[colw];

    // ---- register preloads for G2/G6 ----
    f16x8 Bo2[4], Bh2[4];
    #pragma unroll
    for (int kt = 0; kt < 4; ++kt) {
        Bo2[kt] = Pt[(14 + wq * 4 + kt) * 64 + lane];
        Bh2[kt] = Pt[(128 + wq * 4 + kt) * 64 + lane];
    }

    // ---- init state + pads ----
    float y[4], yo[4] = {0,0,0,0}, zg[4] = {0,0,0,0};
    #pragma unroll
    for (int r = 0; r < 4; ++r) {
        int row = g4 * 4 + r;
        y[r] = prior[(size_t)(m0 + row) * 64 + colw];
        sYb[row * 64 + SWZ(row, colw)] = (_Float16)y[r];
    }
    {   // sH1 pad cols 112..127, both groups (512 elems, 1/thread)
        int row32 = tid >> 4, col = 112 + (tid & 15);
        int t = row32 >> 4, r16 = row32 & 15;
        _Float16* h1 = (_Float16*)(smem + W_BYTES + t * TILEBUF) + 5120;
        h1[r16 * 128 + SWZ(r16, col)] = (_Float16)0.f;
    }
    for (int i = tid; i < 2 * 16 * 32; i += 512) {   // sZR pads, both groups
        int t = i >> 9, rem = i & 511;
        int r16 = rem >> 5, cc = rem & 31;
        int col = (cc < 16) ? (112 + cc) : (224 + cc);
        _Float16* zr = (_Float16*)(smem + W_BYTES + t * TILEBUF) + 7168;
        zr[r16 * 256 + SWZ(r16, col)] = (_Float16)0.f;
    }
    __syncthreads();

    const float t0v = ts[0], t1v = ts[1];

    // ---- x staging: each group's 256 threads own its 512 x-elems (2 each) ----
    const int t8 = tid & 255;
    const int rowA = t8 >> 5, xcol = t8 & 31;   // rows 0..7
    const int rowB = rowA + 8;                  // rows 8..15
    const float* xpA = data + (size_t)(m0 + rowA) * (T_STEPS * 32) + 32 + xcol;
    const float* xpB = data + (size_t)(m0 + rowB) * (T_STEPS * 32) + 32 + xcol;
    const int xswA = rowA * 128 + SWZ(rowA, 64 + xcol);
    const int xswB = rowB * 128 + SWZ(rowB, 64 + xcol);
    float xvA = *xpA, xvB = *xpB;

    // ---- phase bodies (operate on this wave's group buffers/state) ----
    auto PH_STAGEX = [&](int s_) {
        _Float16 a = (_Float16)xvA, b = (_Float16)xvB;
        sYX[xswA] = a; sRX[xswA] = a;
        sYX[xswB] = b; sRX[xswB] = b;
        xpA += 32; xpB += 32;
        if (s_ < T_STEPS - 2) { xvA = *xpA; xvB = *xpB; }
    };
    auto PH_G1 = [&]() {
        f16x8 a0 = ldsA(sYb, 64, c16, (g4 << 3));
        f16x8 a1 = ldsA(sYb, 64, c16, 32 + (g4 << 3));
        #pragma unroll
        for (int t = 0; t < 2; ++t) {
            int nt = wq + 4 * t;
            if (nt < 7) {
                f32x4 acc0 = {b_o1[t], b_o1[t], b_o1[t], b_o1[t]};
                f32x4 z4 = {0.f, 0.f, 0.f, 0.f};
                acc0 = MFMA16(a0, Wv[(nt * 2 + 0) * 64 + lane], acc0);
                f32x4 acc1 = MFMA16(a1, Wv[(nt * 2 + 1) * 64 + lane], z4);
                int col = nt * 16 + c16;
                #pragma unroll
                for (int r = 0; r < 4; ++r) {
                    int row = g4 * 4 + r;
                    sH1[row * 128 + SWZ(row, col)] = (_Float16)fast_tanh(acc0[r] + acc1[r]);
                }
            }
        }
    };
    auto PH_G2 = [&](float dt_) {
        f32x4 acc0 = {b_o2, b_o2, b_o2, b_o2};
        f32x4 z4 = {0.f, 0.f, 0.f, 0.f};
        acc0 = MFMA16(ldsA(sH1, 128, c16, 0 * 32 + (g4 << 3)), Bo2[0], acc0);
        f32x4 acc1 = MFMA16(ldsA(sH1, 128, c16, 1 * 32 + (g4 << 3)), Bo2[1], z4);
        acc0 = MFMA16(ldsA(sH1, 128, c16, 2 * 32 + (g4 << 3)), Bo2[2], acc0);
        acc1 = MFMA16(ldsA(sH1, 128, c16, 3 * 32 + (g4 << 3)), Bo2[3], acc1);
        #pragma unroll
        for (int r = 0; r < 4; ++r) {
            int row = g4 * 4 + r;
            yo[r] = y[r] + dt_ * (acc0[r] + acc1[r]);
            sYX[row * 128 + SWZ(row, colw)] = (_Float16)yo[r];
        }
    };
    auto PH_G3 = [&]() {
        f16x8 a0 = ldsA(sYX, 128, c16, 0 * 32 + (g4 << 3));
        f16x8 a1 = ldsA(sYX, 128, c16, 1 * 32 + (g4 << 3));
        f16x8 a2 = ldsA(sYX, 128, c16, 2 * 32 + (g4 << 3));
        #pragma unroll
        for (int q = 0; q < 4; ++q) {
            int i = wq + 4 * q;
            if (i < 14) {
                int bt = (i < 7) ? i : i + 1;
                f32x4 acc0 = {b_zr[q], b_zr[q], b_zr[q], b_zr[q]};
                f32x4 z4 = {0.f, 0.f, 0.f, 0.f};
                acc0 = MFMA16(a0, Wv[(14 + bt * 3 + 0) * 64 + lane], acc0);
                f32x4 acc1 = MFMA16(a1, Wv[(14 + bt * 3 + 1) * 64 + lane], z4);
                acc0 = MFMA16(a2, Wv[(14 + bt * 3 + 2) * 64 + lane], acc0);
                int col = bt * 16 + c16;
                #pragma unroll
                for (int r = 0; r < 4; ++r) {
                    int row = g4 * 4 + r;
                    sZR[row * 256 + SWZ(row, col)] = (_Float16)fast_tanh(acc0[r] + acc1[r]);
                }
            }
        }
    };
    auto PH_G4 = [&]() {
        f32x4 accz0 = {b_z2, b_z2, b_z2, b_z2};
        f32x4 accr0 = {b_r2, b_r2, b_r2, b_r2};
        f32x4 z4 = {0.f, 0.f, 0.f, 0.f};
        f32x4 accz1 = z4, accr1 = z4;
        accz0 = MFMA16(ldsA(sZR, 256, c16, 0 * 32 + (g4 << 3)), Wv[(59 + wq * 4 + 0) * 64 + lane], accz0);
        accr0 = MFMA16(ldsA(sZR, 256, c16, 128 + 0 * 32 + (g4 << 3)), Wv[(75 + wq * 4 + 0) * 64 + lane], accr0);
        accz1 = MFMA16(ldsA(sZR, 256, c16, 1 * 32 + (g4 << 3)), Wv[(59 + wq * 4 + 1) * 64 + lane], accz1);
        accr1 = MFMA16(ldsA(sZR, 256, c16, 128 + 1 * 32 + (g4 << 3)), Wv[(75 + wq * 4 + 1) * 64 + lane], accr1);
        accz0 = MFMA16(ldsA(sZR, 256, c16, 2 * 32 + (g4 << 3)), Wv[(59 + wq * 4 + 2) * 64 + lane], accz0);
        accr0 = MFMA16(ldsA(sZR, 256, c16, 128 + 2 * 32 + (g4 << 3)), Wv[(75 + wq * 4 + 2) * 64 + lane], accr0);
        accz1 = MFMA16(ldsA(sZR, 256, c16, 3 * 32 + (g4 << 3)), Wv[(59 + wq * 4 + 3) * 64 + lane], accz1);
        accr1 = MFMA16(ldsA(sZR, 256, c16, 128 + 3 * 32 + (g4 << 3)), Wv[(75 + wq * 4 + 3) * 64 + lane], accr1);
        #pragma unroll
        for (int r = 0; r < 4; ++r) {
            int row = g4 * 4 + r;
            zg[r] = fast_sigmoid(accz0[r] + accz1[r]);
            float rv = fast_sigmoid(accr0[r] + accr1[r]) * yo[r];
            sRX[row * 128 + SWZ(row, colw)] = (_Float16)rv;
        }
    };
    auto PH_G5 = [&]() {
        f16x8 a0 = ldsA(sRX, 128, c16, 0 * 32 + (g4 << 3));
        f16x8 a1 = ldsA(sRX, 128, c16, 1 * 32 + (g4 << 3));
        f16x8 a2 = ldsA(sRX, 128, c16, 2 * 32 + (g4 << 3));
        #pragma unroll
        for (int t = 0; t < 2; ++t) {
            int nt = wq + 4 * t;
            if (nt < 7) {
                f32x4 acc0 = {b_h1[t], b_h1[t], b_h1[t], b_h1[t]};
                f32x4 z4 = {0.f, 0.f, 0.f, 0.f};
                acc0 = MFMA16(a0, Wv[(91 + nt * 3 + 0) * 64 + lane], acc0);
                f32x4 acc1 = MFMA16(a1, Wv[(91 + nt * 3 + 1) * 64 + lane], z4);
                acc0 = MFMA16(a2, Wv[(91 + nt * 3 + 2) * 64 + lane], acc0);
                int col = nt * 16 + c16;
                #pragma unroll
                for (int r = 0; r < 4; ++r) {
                    int row = g4 * 4 + r;
                    sH1[row * 128 + SWZ(row, col)] = (_Float16)fast_tanh(acc0[r] + acc1[r]);
                }
            }
        }
    };
    auto PH_G6 = [&]() {
        f32x4 acc0 = {b_h2, b_h2, b_h2, b_h2};
        f32x4 z4 = {0.f, 0.f, 0.f, 0.f};
        acc0 = MFMA16(ldsA(sH1, 128, c16, 0 * 32 + (g4 << 3)), Bh2[0], acc0);
        f32x4 acc1 = MFMA16(ldsA(sH1, 128, c16, 1 * 32 + (g4 << 3)), Bh2[1], z4);
        acc0 = MFMA16(ldsA(sH1, 128, c16, 2 * 32 + (g4 << 3)), Bh2[2], acc0);
        acc1 = MFMA16(ldsA(sH1, 128, c16, 3 * 32 + (g4 << 3)), Bh2[3], acc1);
        #pragma unroll
        for (int r = 0; r < 4; ++r) {
            int row = g4 * 4 + r;
            float h = fast_tanh(acc0[r] + acc1[r]);
            y[r] = (1.f - zg[r]) * h + zg[r] * yo[r];
            sYb[row * 64 + SWZ(row, colw)] = (_Float16)y[r];
        }
    };

    // ---- staggered main loop: group 1 runs one phase behind group 0 ----
    #pragma unroll 1
    for (int s = 0; s < T_STEPS - 1; ++s) {
        const float dt = (s == 0) ? (t1v - t0v) : (ts[s - 1] - ts[s]);

        if (tg == 0) { PH_G1(); PH_STAGEX(s); } else if (s > 0) { PH_G6(); }
        __syncthreads();
        if (tg == 0) { PH_G2(dt); } else { PH_G1(); PH_STAGEX(s); }
        __syncthreads();
        if (tg == 0) { PH_G3(); } else { PH_G2(dt); }
        __syncthreads();
        if (tg == 0) { PH_G4(); } else { PH_G3(); }
        __syncthreads();
        if (tg == 0) { PH_G5(); } else { PH_G4(); }
        __syncthreads();
        if (tg == 0) { PH_G6(); } else { PH_G5(); }
        __syncthreads();
    }
    if (tg == 1) { PH_G6(); }   // finish step 98 for group 1

    #pragma unroll
    for (int r = 0; r < 4; ++r) {
        int row = g4 * 4 + r;
        out[(size_t)(m0 + row) * 64 + colw] = y[r];
    }
}

extern "C" void kernel_launch(void* const* d_in, const int* in_sizes, int n_in,
                              void* d_out, int out_size, void* d_ws, size_t ws_size,
                              hipStream_t stream) {
    const float* data = (const float*)d_in[0];
    const float* ts   = (const float*)d_in[1];
    const float* prior= (const float*)d_in[2];
    const float* Wo1 = (const float*)d_in[3];  const float* bo1 = (const float*)d_in[4];
    const float* Wo2 = (const float*)d_in[5];  const float* bo2 = (const float*)d_in[6];
    const float* Wz1 = (const float*)d_in[7];  const float* bz1 = (const float*)d_in[8];
    const float* Wz2 = (const float*)d_in[9];  const float* bz2 = (const float*)d_in[10];
    const float* Wr1 = (const float*)d_in[11]; const float* br1 = (const float*)d_in[12];
    const float* Wr2 = (const float*)d_in[13]; const float* br2 = (const float*)d_in[14];
    const float* Wh1 = (const float*)d_in[15]; const float* bh1 = (const float*)d_in[16];
    const float* Wh2 = (const float*)d_in[17]; const float* bh2 = (const float*)d_in[18];
    _Float16* P = (_Float16*)d_ws;
    float* out = (float*)d_out;

    hipFuncSetAttribute((const void*)odernn_kernel,
                        hipFuncAttributeMaxDynamicSharedMemorySize, LDS_TOTAL);

    hipLaunchKernelGGL(pack_kernel, dim3((144 * 512 + 255) / 256), dim3(256), 0, stream,
                       Wo1, Wo2, Wz1, Wz2, Wr1, Wr2, Wh1, Wh2, P);
    hipLaunchKernelGGL(odernn_kernel, dim3(NTRAJ / MBLK), dim3(512), LDS_TOTAL, stream,
                       data, ts, prior, bo1, bo2, bz1, bz2, br1, br2, bh1, bh2, P, out);
}

// Round 10
// 304.991 us; speedup vs baseline: 1.7115x; 1.2539x over previous
//
#include <hip/hip_runtime.h>

#define T_STEPS 100
#define NTRAJ   8192
#define MBLK    32     // two 16-row tile groups per block
#define W_TILES 112
#define W_BYTES (W_TILES * 1024)            // 114688: G1/G3/G4/G5 weights in LDS
#define TILEBUF 22528                       // per-group activation buffers
#define LDS_TOTAL (W_BYTES + 2 * TILEBUF)   // 159744 <= 163840

typedef __attribute__((ext_vector_type(8))) _Float16 f16x8;
typedef __attribute__((ext_vector_type(4))) _Float16 f16x4;
typedef __attribute__((ext_vector_type(4))) float    f32x4;

#define MFMA16(a, b, c) __builtin_amdgcn_mfma_f32_16x16x32_f16((a), (b), (c), 0, 0, 0)

// XOR swizzle on element index within a row (2B elems; XOR elem bits 3..5)
#define SWZ(row, col) ((col) ^ (((row) & 7) << 3))

__device__ __forceinline__ float fast_tanh(float x) {
    float e = __expf(2.f * x);
    return 1.f - 2.f * __builtin_amdgcn_rcpf(1.f + e);
}
__device__ __forceinline__ float fast_sigmoid(float x) {
    float e = __expf(-x);
    return __builtin_amdgcn_rcpf(1.f + e);
}

// ---------------------------------------------------------------------------
// Weight packing (UNCHANGED mapping): tile = 512 f16, element (lane, j) =
// W[k][n] with k = kt*32 + (lane>>4)*8 + j, n = nt*16 + (lane&15).
// Under the swapped-operand scheme this same fragment serves as the
// A-operand of W^T (M = out-feature = lane&15, K = in-feature).
//   [0,14) G1 | [14,30) G2 | [30,75) G3 | [75,107) G4 | [107,128) G5 | [128,144) G6
// ---------------------------------------------------------------------------
__global__ void pack_kernel(const float* __restrict__ Wo1, const float* __restrict__ Wo2,
                            const float* __restrict__ Wz1, const float* __restrict__ Wz2,
                            const float* __restrict__ Wr1, const float* __restrict__ Wr2,
                            const float* __restrict__ Wh1, const float* __restrict__ Wh2,
                            _Float16* __restrict__ P)
{
    int idx = blockIdx.x * 256 + threadIdx.x;
    if (idx >= 144 * 512) return;
    int tile = idx >> 9;
    int r    = idx & 511;
    int lane = r >> 3, j = r & 7;
    int krel = ((lane >> 4) << 3) + j;   // 0..31
    int c16  = lane & 15;
    float val = 0.f;

    if (tile < 14) {                       // ODE L1
        int t = tile, nt = t >> 1, kt = t & 1;
        int k = kt * 32 + krel, n = nt * 16 + c16;
        if (k < 64 && n < 100) val = Wo1[k * 100 + n];
    } else if (tile < 30) {                // ODE L2
        int t = tile - 14, nt = t >> 2, kt = t & 3;
        int k = kt * 32 + krel, n = nt * 16 + c16;
        if (k < 100) val = Wo2[k * 64 + n];
    } else if (tile < 75) {                // ZR L1
        int t = tile - 30, nt = t / 3, kt = t % 3;
        int k = kt * 32 + krel;            // K = 96 exact
        if (nt < 7)      { int n = nt * 16 + c16;        if (n < 100) val = Wz1[k * 100 + n]; }
        else if (nt >= 8){ int n = (nt - 8) * 16 + c16;  if (n < 100) val = Wr1[k * 100 + n]; }
    } else if (tile < 107) {               // ZR L2
        int t = tile - 75, gate = t >> 4, rem = t & 15, nt = rem >> 2, kt = rem & 3;
        int k = kt * 32 + krel, n = nt * 16 + c16;
        const float* W = gate ? Wr2 : Wz2;
        if (k < 100) val = W[k * 64 + n];
    } else if (tile < 128) {               // H L1
        int t = tile - 107, nt = t / 3, kt = t % 3;
        int k = kt * 32 + krel, n = nt * 16 + c16;
        if (n < 100) val = Wh1[k * 100 + n];
    } else {                               // H L2
        int t = tile - 128, nt = t >> 2, kt = t & 3;
        int k = kt * 32 + krel, n = nt * 16 + c16;
        if (k < 100) val = Wh2[k * 64 + n];
    }
    P[idx] = (_Float16)val;
}

// activation fragment read (B-operand): n = traj = lane&15, k-slice contiguous
__device__ __forceinline__ f16x8 ldsA(const _Float16* buf, int stride, int row, int kcol) {
    return *(const f16x8*)(buf + row * stride + SWZ(row, kcol));
}
// contiguous 4-feature epilogue store (one b64 instead of 4 scattered b16)
__device__ __forceinline__ void st4(_Float16* buf, int stride, int traj, int f0,
                                    float a, float b, float c, float d) {
    f16x4 h = {(_Float16)a, (_Float16)b, (_Float16)c, (_Float16)d};
    *(f16x4*)(buf + traj * stride + SWZ(traj, f0)) = h;
}
__device__ __forceinline__ f32x4 loadBias4(const float* b, int f0, int n) {
    f32x4 v = {0.f, 0.f, 0.f, 0.f};
    #pragma unroll
    for (int r = 0; r < 4; ++r) if (f0 + r < n) v[r] = b[f0 + r];
    return v;
}

// ---------------------------------------------------------------------------
// Main kernel = R6 skeleton (351us best; stagger of R8 reverted) with SWAPPED
// MFMA operands: A = weights, B = activations -> C col = trajectory,
// C rows = 4 consecutive out-features per lane. Every epilogue is one b64
// write; prior/out are float4; biases fold into C-init as per-r vectors.
// Activation layout, weight pack, and fragment reads are unchanged.
// ---------------------------------------------------------------------------
__global__ __launch_bounds__(512, 2) void odernn_kernel(
    const float* __restrict__ data, const float* __restrict__ ts,
    const float* __restrict__ prior,
    const float* __restrict__ bo1, const float* __restrict__ bo2,
    const float* __restrict__ bz1, const float* __restrict__ bz2,
    const float* __restrict__ br1, const float* __restrict__ br2,
    const float* __restrict__ bh1, const float* __restrict__ bh2,
    const _Float16* __restrict__ P, float* __restrict__ out)
{
    extern __shared__ __align__(16) char smem[];
    _Float16* W = (_Float16*)smem;        // 112 tiles: G1[0,14) G3[14,59) G4[59,91) G5[91,112)

    const int tid  = threadIdx.x;
    const int lane = tid & 63;
    const int wv   = tid >> 6;            // 0..7
    const int tg   = wv >> 2;             // tile group 0/1
    const int wq   = wv & 3;              // wave-in-group
    const int c16  = lane & 15;           // trajectory within group
    const int g4   = lane >> 4;
    const int m0b  = blockIdx.x * MBLK;
    const int m0   = m0b + tg * 16;
    const int f0   = wq * 16 + (g4 << 2); // this lane's own 4-feature base (tile nt=wq)
    const f16x8* Pt = (const f16x8*)P;
    const f16x8* Wv = (const f16x8*)W;

    _Float16* base = (_Float16*)(smem + W_BYTES + tg * TILEBUF);
    _Float16* sYb = base;                 // [16 traj][64 feat]
    _Float16* sYX = base + 1024;          // [16][128] [yode | x]
    _Float16* sRX = base + 3072;          // [16][128] [rg*yode | x]
    _Float16* sH1 = base + 5120;          // [16][128]
    _Float16* sZR = base + 7168;          // [16][256] [zh(112)+pad | rh(112)+pad]

    // ---- stage G1/G3/G4/G5 weights into LDS ----
    {
        f16x8* Wd = (f16x8*)W;
        #pragma unroll
        for (int it = 0; it < 14; ++it) {
            int idx = tid + it * 512;
            int ldst = idx >> 6, l = idx & 63;
            int srct = (ldst < 14) ? ldst : ldst + 16;   // skip G2 range
            Wd[idx] = Pt[srct * 64 + l];
        }
    }

    // ---- biases as per-lane f32x4 (feature vectors) ----
    f32x4 bo1v[2], bh1v[2], bzrv[4];
    #pragma unroll
    for (int t = 0; t < 2; ++t) {
        int nt = wq + 4 * t;
        f32x4 zo = {0.f,0.f,0.f,0.f};
        if (nt < 7) {
            int ft = nt * 16 + (g4 << 2);
            bo1v[t] = loadBias4(bo1, ft, 100);
            bh1v[t] = loadBias4(bh1, ft, 100);
        } else { bo1v[t] = zo; bh1v[t] = zo; }
    }
    #pragma unroll
    for (int q = 0; q < 4; ++q) {
        int i = wq + 4 * q;
        f32x4 v = {0.f,0.f,0.f,0.f};
        if (i < 14) {
            int bt = (i < 7) ? i : i + 1;
            int ft = bt * 16 + (g4 << 2);
            if (i < 7) v = loadBias4(bz1, ft, 100);
            else       v = loadBias4(br1, ft - 128, 100);
        }
        bzrv[q] = v;
    }
    const f32x4 bo2v = *(const f32x4*)(bo2 + f0);
    const f32x4 bz2v = *(const f32x4*)(bz2 + f0);
    const f32x4 br2v = *(const f32x4*)(br2 + f0);
    const f32x4 bh2v = *(const f32x4*)(bh2 + f0);

    // ---- register A-frags (weights) for short dependent phases G2/G6 ----
    f16x8 Ao2[4], Ah2[4];
    #pragma unroll
    for (int kt = 0; kt < 4; ++kt) {
        Ao2[kt] = Pt[(14 + wq * 4 + kt) * 64 + lane];
        Ah2[kt] = Pt[(128 + wq * 4 + kt) * 64 + lane];
    }

    // ---- init state: lane owns traj c16, feats f0..f0+3 (float4 IO) ----
    float y[4], yo[4] = {0,0,0,0}, zg[4] = {0,0,0,0};
    {
        f32x4 pv = *(const f32x4*)(prior + (size_t)(m0 + c16) * 64 + f0);
        #pragma unroll
        for (int r = 0; r < 4; ++r) y[r] = pv[r];
        st4(sYb, 64, c16, f0, y[0], y[1], y[2], y[3]);
    }
    {   // sH1 pad feats 112..127, both groups (512 elems, 1/thread)
        int row32 = tid >> 4, col = 112 + (tid & 15);
        int t = row32 >> 4, r16 = row32 & 15;
        _Float16* h1 = (_Float16*)(smem + W_BYTES + t * TILEBUF) + 5120;
        h1[r16 * 128 + SWZ(r16, col)] = (_Float16)0.f;
    }
    for (int i = tid; i < 2 * 16 * 32; i += 512) {   // sZR pads, both groups
        int t = i >> 9, rem = i & 511;
        int r16 = rem >> 5, cc = rem & 31;
        int col = (cc < 16) ? (112 + cc) : (224 + cc);
        _Float16* zr = (_Float16*)(smem + W_BYTES + t * TILEBUF) + 7168;
        zr[r16 * 256 + SWZ(r16, col)] = (_Float16)0.f;
    }
    __syncthreads();

    const float t0v = ts[0], t1v = ts[1];

    // ---- x staging: group's 256 threads own its 512 x-elems (2 each) ----
    const int t8 = tid & 255;
    const int rowA = t8 >> 5, xcol = t8 & 31;   // traj rows 0..7
    const int rowB = rowA + 8;                  // traj rows 8..15
    const float* xpA = data + (size_t)(m0 + rowA) * (T_STEPS * 32) + 32 + xcol;
    const float* xpB = data + (size_t)(m0 + rowB) * (T_STEPS * 32) + 32 + xcol;
    const int xswA = rowA * 128 + SWZ(rowA, 64 + xcol);
    const int xswB = rowB * 128 + SWZ(rowB, 64 + xcol);
    float xvA = *xpA, xvB = *xpB;

    #pragma unroll 1
    for (int s = 0; s < T_STEPS - 1; ++s) {
        const float dt = (s == 0) ? (t1v - t0v) : (ts[s - 1] - ts[s]);

        // ---- G1: H1 = tanh(Wo1^T @ y^T) — wave w<7-ish owns tiles nt=wq,wq+4 ----
        {
            f16x8 b0 = ldsA(sYb, 64, c16, (g4 << 3));
            f16x8 b1 = ldsA(sYb, 64, c16, 32 + (g4 << 3));
            #pragma unroll
            for (int t = 0; t < 2; ++t) {
                int nt = wq + 4 * t;
                if (nt < 7) {
                    f32x4 acc0 = bo1v[t];
                    f32x4 z4 = {0.f, 0.f, 0.f, 0.f};
                    acc0 = MFMA16(Wv[(nt * 2 + 0) * 64 + lane], b0, acc0);
                    f32x4 acc1 = MFMA16(Wv[(nt * 2 + 1) * 64 + lane], b1, z4);
                    int ft = nt * 16 + (g4 << 2);
                    st4(sH1, 128, c16, ft,
                        fast_tanh(acc0[0] + acc1[0]), fast_tanh(acc0[1] + acc1[1]),
                        fast_tanh(acc0[2] + acc1[2]), fast_tanh(acc0[3] + acc1[3]));
                }
            }
        }
        // stage current x into both concat buffers
        {
            _Float16 a = (_Float16)xvA, b = (_Float16)xvB;
            sYX[xswA] = a; sRX[xswA] = a;
            sYX[xswB] = b; sRX[xswB] = b;
            xpA += 32; xpB += 32;
            if (s < T_STEPS - 2) { xvA = *xpA; xvB = *xpB; }
        }
        __syncthreads();

        // ---- G2: yode = y + dt*(Wo2^T @ H1^T + b) ----
        {
            f32x4 acc0 = bo2v;
            f32x4 z4 = {0.f, 0.f, 0.f, 0.f};
            acc0 = MFMA16(Ao2[0], ldsA(sH1, 128, c16, 0 * 32 + (g4 << 3)), acc0);
            f32x4 acc1 = MFMA16(Ao2[1], ldsA(sH1, 128, c16, 1 * 32 + (g4 << 3)), z4);
            acc0 = MFMA16(Ao2[2], ldsA(sH1, 128, c16, 2 * 32 + (g4 << 3)), acc0);
            acc1 = MFMA16(Ao2[3], ldsA(sH1, 128, c16, 3 * 32 + (g4 << 3)), acc1);
            #pragma unroll
            for (int r = 0; r < 4; ++r) yo[r] = y[r] + dt * (acc0[r] + acc1[r]);
            st4(sYX, 128, c16, f0, yo[0], yo[1], yo[2], yo[3]);
        }
        __syncthreads();

        // ---- G3: zr-hidden = tanh(W{z,r}1^T @ [yode|x]^T + b) ----
        {
            f16x8 b0 = ldsA(sYX, 128, c16, 0 * 32 + (g4 << 3));
            f16x8 b1 = ldsA(sYX, 128, c16, 1 * 32 + (g4 << 3));
            f16x8 b2 = ldsA(sYX, 128, c16, 2 * 32 + (g4 << 3));
            #pragma unroll
            for (int q = 0; q < 4; ++q) {
                int i = wq + 4 * q;
                if (i < 14) {
                    int bt = (i < 7) ? i : i + 1;
                    f32x4 acc0 = bzrv[q];
                    f32x4 z4 = {0.f, 0.f, 0.f, 0.f};
                    acc0 = MFMA16(Wv[(14 + bt * 3 + 0) * 64 + lane], b0, acc0);
                    f32x4 acc1 = MFMA16(Wv[(14 + bt * 3 + 1) * 64 + lane], b1, z4);
                    acc0 = MFMA16(Wv[(14 + bt * 3 + 2) * 64 + lane], b2, acc0);
                    int ft = bt * 16 + (g4 << 2);
                    st4(sZR, 256, c16, ft,
                        fast_tanh(acc0[0] + acc1[0]), fast_tanh(acc0[1] + acc1[1]),
                        fast_tanh(acc0[2] + acc1[2]), fast_tanh(acc0[3] + acc1[3]));
                }
            }
        }
        __syncthreads();

        // ---- G4: z-gate -> regs ; r-gate * yode -> sRX (same lane owns both) ----
        {
            f32x4 accz0 = bz2v, accr0 = br2v;
            f32x4 z4 = {0.f, 0.f, 0.f, 0.f};
            f32x4 accz1 = z4, accr1 = z4;
            accz0 = MFMA16(Wv[(59 + wq * 4 + 0) * 64 + lane], ldsA(sZR, 256, c16, 0 * 32 + (g4 << 3)), accz0);
            accr0 = MFMA16(Wv[(75 + wq * 4 + 0) * 64 + lane], ldsA(sZR, 256, c16, 128 + 0 * 32 + (g4 << 3)), accr0);
            accz1 = MFMA16(Wv[(59 + wq * 4 + 1) * 64 + lane], ldsA(sZR, 256, c16, 1 * 32 + (g4 << 3)), accz1);
            accr1 = MFMA16(Wv[(75 + wq * 4 + 1) * 64 + lane], ldsA(sZR, 256, c16, 128 + 1 * 32 + (g4 << 3)), accr1);
            accz0 = MFMA16(Wv[(59 + wq * 4 + 2) * 64 + lane], ldsA(sZR, 256, c16, 2 * 32 + (g4 << 3)), accz0);
            accr0 = MFMA16(Wv[(75 + wq * 4 + 2) * 64 + lane], ldsA(sZR, 256, c16, 128 + 2 * 32 + (g4 << 3)), accr0);
            accz1 = MFMA16(Wv[(59 + wq * 4 + 3) * 64 + lane], ldsA(sZR, 256, c16, 3 * 32 + (g4 << 3)), accz1);
            accr1 = MFMA16(Wv[(75 + wq * 4 + 3) * 64 + lane], ldsA(sZR, 256, c16, 128 + 3 * 32 + (g4 << 3)), accr1);
            float rv[4];
            #pragma unroll
            for (int r = 0; r < 4; ++r) {
                zg[r] = fast_sigmoid(accz0[r] + accz1[r]);
                rv[r] = fast_sigmoid(accr0[r] + accr1[r]) * yo[r];
            }
            st4(sRX, 128, c16, f0, rv[0], rv[1], rv[2], rv[3]);
        }
        __syncthreads();

        // ---- G5: H1 = tanh(Wh1^T @ [rg*yode|x]^T + b) ----
        {
            f16x8 b0 = ldsA(sRX, 128, c16, 0 * 32 + (g4 << 3));
            f16x8 b1 = ldsA(sRX, 128, c16, 1 * 32 + (g4 << 3));
            f16x8 b2 = ldsA(sRX, 128, c16, 2 * 32 + (g4 << 3));
            #pragma unroll
            for (int t = 0; t < 2; ++t) {
                int nt = wq + 4 * t;
                if (nt < 7) {
                    f32x4 acc0 = bh1v[t];
                    f32x4 z4 = {0.f, 0.f, 0.f, 0.f};
                    acc0 = MFMA16(Wv[(91 + nt * 3 + 0) * 64 + lane], b0, acc0);
                    f32x4 acc1 = MFMA16(Wv[(91 + nt * 3 + 1) * 64 + lane], b1, z4);
                    acc0 = MFMA16(Wv[(91 + nt * 3 + 2) * 64 + lane], b2, acc0);
                    int ft = nt * 16 + (g4 << 2);
                    st4(sH1, 128, c16, ft,
                        fast_tanh(acc0[0] + acc1[0]), fast_tanh(acc0[1] + acc1[1]),
                        fast_tanh(acc0[2] + acc1[2]), fast_tanh(acc0[3] + acc1[3]));
                }
            }
        }
        __syncthreads();

        // ---- G6: h = tanh(Wh2^T @ H1^T + b); y = (1-z)*h + z*yode ----
        {
            f32x4 acc0 = bh2v;
            f32x4 z4 = {0.f, 0.f, 0.f, 0.f};
            acc0 = MFMA16(Ah2[0], ldsA(sH1, 128, c16, 0 * 32 + (g4 << 3)), acc0);
            f32x4 acc1 = MFMA16(Ah2[1], ldsA(sH1, 128, c16, 1 * 32 + (g4 << 3)), z4);
            acc0 = MFMA16(Ah2[2], ldsA(sH1, 128, c16, 2 * 32 + (g4 << 3)), acc0);
            acc1 = MFMA16(Ah2[3], ldsA(sH1, 128, c16, 3 * 32 + (g4 << 3)), acc1);
            #pragma unroll
            for (int r = 0; r < 4; ++r) {
                float h = fast_tanh(acc0[r] + acc1[r]);
                y[r] = (1.f - zg[r]) * h + zg[r] * yo[r];
            }
            st4(sYb, 64, c16, f0, y[0], y[1], y[2], y[3]);
        }
        __syncthreads();
    }

    {
        f32x4 ov = {y[0], y[1], y[2], y[3]};
        *(f32x4*)(out + (size_t)(m0 + c16) * 64 + f0) = ov;
    }
}

extern "C" void kernel_launch(void* const* d_in, const int* in_sizes, int n_in,
                              void* d_out, int out_size, void* d_ws, size_t ws_size,
                              hipStream_t stream) {
    const float* data = (const float*)d_in[0];
    const float* ts   = (const float*)d_in[1];
    const float* prior= (const float*)d_in[2];
    const float* Wo1 = (const float*)d_in[3];  const float* bo1 = (const float*)d_in[4];
    const float* Wo2 = (const float*)d_in[5];  const float* bo2 = (const float*)d_in[6];
    const float* Wz1 = (const float*)d_in[7];  const float* bz1 = (const float*)d_in[8];
    const float* Wz2 = (const float*)d_in[9];  const float* bz2 = (const float*)d_in[10];
    const float* Wr1 = (const float*)d_in[11]; const float* br1 = (const float*)d_in[12];
    const float* Wr2 = (const float*)d_in[13]; const float* br2 = (const float*)d_in[14];
    const float* Wh1 = (const float*)d_in[15]; const float* bh1 = (const float*)d_in[16];
    const float* Wh2 = (const float*)d_in[17]; const float* bh2 = (const float*)d_in[18];
    _Float16* P = (_Float16*)d_ws;
    float* out = (float*)d_out;

    hipFuncSetAttribute((const void*)odernn_kernel,
                        hipFuncAttributeMaxDynamicSharedMemorySize, LDS_TOTAL);

    hipLaunchKernelGGL(pack_kernel, dim3((144 * 512 + 255) / 256), dim3(256), 0, stream,
                       Wo1, Wo2, Wz1, Wz2, Wr1, Wr2, Wh1, Wh2, P);
    hipLaunchKernelGGL(odernn_kernel, dim3(NTRAJ / MBLK), dim3(512), LDS_TOTAL, stream,
                       data, ts, prior, bo1, bo2, bz1, bz2, br1, br2, bh1, bh2, P, out);
}

// Round 12
// 298.882 us; speedup vs baseline: 1.7465x; 1.0204x over previous
//
#include <hip/hip_runtime.h>

#define T_STEPS 100
#define NTRAJ   8192
#define MBLK    32     // two 16-row tile groups per block
#define W_TILES 112
#define W_BYTES (W_TILES * 1024)            // 114688: G1/G3/G4/G5 weights in LDS
#define TILEBUF 18432                       // per-group activation buffers (x removed)
#define LDS_TOTAL (W_BYTES + 2 * TILEBUF)   // 151552 <= 163840

typedef __attribute__((ext_vector_type(8))) _Float16 f16x8;
typedef __attribute__((ext_vector_type(4))) _Float16 f16x4;
typedef __attribute__((ext_vector_type(2))) __fp16   h16x2;   // cvt_pkrtz return type
typedef __attribute__((ext_vector_type(4))) float    f32x4;

#define MFMA16(a, b, c) __builtin_amdgcn_mfma_f32_16x16x32_f16((a), (b), (c), 0, 0, 0)

// XOR swizzle on element index within a row (2B elems; XOR elem bits 3..5)
#define SWZ(row, col) ((col) ^ (((row) & 7) << 3))

__device__ __forceinline__ float fast_tanh(float x) {
    float e = __expf(2.f * x);
    return 1.f - 2.f * __builtin_amdgcn_rcpf(1.f + e);
}
__device__ __forceinline__ float fast_sigmoid(float x) {
    float e = __expf(-x);
    return __builtin_amdgcn_rcpf(1.f + e);
}

// ---------------------------------------------------------------------------
// Weight packing (UNCHANGED): tile = 512 f16, element (lane, j) = W[k][n],
// k = kt*32 + (lane>>4)*8 + j, n = nt*16 + (lane&15). Serves as A-operand of
// W^T under swapped-operand MFMA.
//   [0,14) G1 | [14,30) G2 | [30,75) G3 | [75,107) G4 | [107,128) G5 | [128,144) G6
// ---------------------------------------------------------------------------
__global__ void pack_kernel(const float* __restrict__ Wo1, const float* __restrict__ Wo2,
                            const float* __restrict__ Wz1, const float* __restrict__ Wz2,
                            const float* __restrict__ Wr1, const float* __restrict__ Wr2,
                            const float* __restrict__ Wh1, const float* __restrict__ Wh2,
                            _Float16* __restrict__ P)
{
    int idx = blockIdx.x * 256 + threadIdx.x;
    if (idx >= 144 * 512) return;
    int tile = idx >> 9;
    int r    = idx & 511;
    int lane = r >> 3, j = r & 7;
    int krel = ((lane >> 4) << 3) + j;   // 0..31
    int c16  = lane & 15;
    float val = 0.f;

    if (tile < 14) {                       // ODE L1
        int t = tile, nt = t >> 1, kt = t & 1;
        int k = kt * 32 + krel, n = nt * 16 + c16;
        if (k < 64 && n < 100) val = Wo1[k * 100 + n];
    } else if (tile < 30) {                // ODE L2
        int t = tile - 14, nt = t >> 2, kt = t & 3;
        int k = kt * 32 + krel, n = nt * 16 + c16;
        if (k < 100) val = Wo2[k * 64 + n];
    } else if (tile < 75) {                // ZR L1
        int t = tile - 30, nt = t / 3, kt = t % 3;
        int k = kt * 32 + krel;            // K = 96 exact
        if (nt < 7)      { int n = nt * 16 + c16;        if (n < 100) val = Wz1[k * 100 + n]; }
        else if (nt >= 8){ int n = (nt - 8) * 16 + c16;  if (n < 100) val = Wr1[k * 100 + n]; }
    } else if (tile < 107) {               // ZR L2
        int t = tile - 75, gate = t >> 4, rem = t & 15, nt = rem >> 2, kt = rem & 3;
        int k = kt * 32 + krel, n = nt * 16 + c16;
        const float* W = gate ? Wr2 : Wz2;
        if (k < 100) val = W[k * 64 + n];
    } else if (tile < 128) {               // H L1
        int t = tile - 107, nt = t / 3, kt = t % 3;
        int k = kt * 32 + krel, n = nt * 16 + c16;
        if (n < 100) val = Wh1[k * 100 + n];
    } else {                               // H L2
        int t = tile - 128, nt = t >> 2, kt = t & 3;
        int k = kt * 32 + krel, n = nt * 16 + c16;
        if (k < 100) val = Wh2[k * 64 + n];
    }
    P[idx] = (_Float16)val;
}

// activation B-fragment read: n = traj = lane&15, k-slice contiguous 8
__device__ __forceinline__ f16x8 ldsA(const _Float16* buf, int stride, int row, int kcol) {
    return *(const f16x8*)(buf + row * stride + SWZ(row, kcol));
}
// contiguous 4-feature epilogue store (one b64)
__device__ __forceinline__ void st4(_Float16* buf, int stride, int traj, int f0,
                                    float a, float b, float c, float d) {
    f16x4 h = {(_Float16)a, (_Float16)b, (_Float16)c, (_Float16)d};
    *(f16x4*)(buf + traj * stride + SWZ(traj, f0)) = h;
}
__device__ __forceinline__ f32x4 loadBias4(const float* b, int f0, int n) {
    f32x4 v = {0.f, 0.f, 0.f, 0.f};
    #pragma unroll
    for (int r = 0; r < 4; ++r) if (f0 + r < n) v[r] = b[f0 + r];
    return v;
}
// pack 8 f32 (two f32x4) -> f16x8 via cvt_pkrtz
__device__ __forceinline__ f16x8 cvt8(f32x4 a, f32x4 b) {
    union { h16x2 h2[4]; f16x8 v; } u;
    u.h2[0] = __builtin_amdgcn_cvt_pkrtz(a[0], a[1]);
    u.h2[1] = __builtin_amdgcn_cvt_pkrtz(a[2], a[3]);
    u.h2[2] = __builtin_amdgcn_cvt_pkrtz(b[0], b[1]);
    u.h2[3] = __builtin_amdgcn_cvt_pkrtz(b[2], b[3]);
    return u.v;
}

// ---------------------------------------------------------------------------
// R9 skeleton (305us best) + x-as-register-B-fragment:
//  - x loaded direct from global in fragment shape (2 float4/lane), one step
//    ahead, issued at slot-1 top so G1 work covers the L2 latency.
//  - G3/G5's x K-slice (kt=2) pre-accumulated into registers during the
//    light G1/G2 slots -> heavy slots lose 1/3 of their MFMAs and ds_reads.
//  - LDS x staging deleted; sYX/sRX are [16][64].
// ---------------------------------------------------------------------------
__global__ __launch_bounds__(512, 2) void odernn_kernel(
    const float* __restrict__ data, const float* __restrict__ ts,
    const float* __restrict__ prior,
    const float* __restrict__ bo1, const float* __restrict__ bo2,
    const float* __restrict__ bz1, const float* __restrict__ bz2,
    const float* __restrict__ br1, const float* __restrict__ br2,
    const float* __restrict__ bh1, const float* __restrict__ bh2,
    const _Float16* __restrict__ P, float* __restrict__ out)
{
    extern __shared__ __align__(16) char smem[];
    _Float16* W = (_Float16*)smem;        // 112 tiles: G1[0,14) G3[14,59) G4[59,91) G5[91,112)

    const int tid  = threadIdx.x;
    const int lane = tid & 63;
    const int wv   = tid >> 6;            // 0..7
    const int tg   = wv >> 2;             // tile group 0/1
    const int wq   = wv & 3;              // wave-in-group
    const int c16  = lane & 15;           // trajectory within group
    const int g4   = lane >> 4;
    const int m0   = blockIdx.x * MBLK + tg * 16;
    const int f0   = wq * 16 + (g4 << 2); // lane's own 4-feature base (tile nt=wq)
    const f16x8* Pt = (const f16x8*)P;
    const f16x8* Wv = (const f16x8*)W;

    _Float16* base = (_Float16*)(smem + W_BYTES + tg * TILEBUF);
    _Float16* sYb = base;                 // [16][64]  y
    _Float16* sYX = base + 1024;          // [16][64]  yode
    _Float16* sRX = base + 2048;          // [16][64]  rg*yode
    _Float16* sH1 = base + 3072;          // [16][128] hidden
    _Float16* sZR = base + 5120;          // [16][256] [zh|rh] + pads

    // ---- stage G1/G3/G4/G5 weights into LDS ----
    {
        f16x8* Wd = (f16x8*)W;
        #pragma unroll
        for (int it = 0; it < 14; ++it) {
            int idx = tid + it * 512;
            int ldst = idx >> 6, l = idx & 63;
            int srct = (ldst < 14) ? ldst : ldst + 16;   // skip G2 range
            Wd[idx] = Pt[srct * 64 + l];
        }
    }

    // ---- biases as per-lane f32x4 feature vectors ----
    f32x4 bo1v[2], bh1v[2], bzrv[4];
    #pragma unroll
    for (int t = 0; t < 2; ++t) {
        int nt = wq + 4 * t;
        f32x4 zo = {0.f,0.f,0.f,0.f};
        if (nt < 7) {
            int ft = nt * 16 + (g4 << 2);
            bo1v[t] = loadBias4(bo1, ft, 100);
            bh1v[t] = loadBias4(bh1, ft, 100);
        } else { bo1v[t] = zo; bh1v[t] = zo; }
    }
    #pragma unroll
    for (int q = 0; q < 4; ++q) {
        int i = wq + 4 * q;
        f32x4 v = {0.f,0.f,0.f,0.f};
        if (i < 14) {
            int bt = (i < 7) ? i : i + 1;
            int ft = bt * 16 + (g4 << 2);
            if (i < 7) v = loadBias4(bz1, ft, 100);
            else       v = loadBias4(br1, ft - 128, 100);
        }
        bzrv[q] = v;
    }
    const f32x4 bo2v = *(const f32x4*)(bo2 + f0);
    const f32x4 bz2v = *(const f32x4*)(bz2 + f0);
    const f32x4 br2v = *(const f32x4*)(br2 + f0);
    const f32x4 bh2v = *(const f32x4*)(bh2 + f0);

    // ---- register A-frags (weights) for short dependent phases G2/G6 ----
    f16x8 Ao2[4], Ah2[4];
    #pragma unroll
    for (int kt = 0; kt < 4; ++kt) {
        Ao2[kt] = Pt[(14 + wq * 4 + kt) * 64 + lane];
        Ah2[kt] = Pt[(128 + wq * 4 + kt) * 64 + lane];
    }

    // ---- init state ----
    float y[4], yo[4] = {0,0,0,0}, zg[4] = {0,0,0,0};
    {
        f32x4 pv = *(const f32x4*)(prior + (size_t)(m0 + c16) * 64 + f0);
        #pragma unroll
        for (int r = 0; r < 4; ++r) y[r] = pv[r];
        st4(sYb, 64, c16, f0, y[0], y[1], y[2], y[3]);
    }
    {   // sH1 pad feats 112..127, both groups (512 elems, 1/thread)
        int row32 = tid >> 4, col = 112 + (tid & 15);
        int t = row32 >> 4, r16 = row32 & 15;
        _Float16* h1 = (_Float16*)(smem + W_BYTES + t * TILEBUF) + 3072;
        h1[r16 * 128 + SWZ(r16, col)] = (_Float16)0.f;
    }
    for (int i = tid; i < 2 * 16 * 32; i += 512) {   // sZR pads, both groups
        int t = i >> 9, rem = i & 511;
        int r16 = rem >> 5, cc = rem & 31;
        int col = (cc < 16) ? (112 + cc) : (224 + cc);
        _Float16* zr = (_Float16*)(smem + W_BYTES + t * TILEBUF) + 5120;
        zr[r16 * 256 + SWZ(r16, col)] = (_Float16)0.f;
    }
    __syncthreads();

    const float t0v = ts[0], t1v = ts[1];

    // ---- x fragment: lane owns x[traj=c16][feat g4*8 .. g4*8+7] ----
    const float* xptr = data + (size_t)(m0 + c16) * (T_STEPS * 32) + 32 + (g4 << 3);
    f32x4 xn0 = *(const f32x4*)(xptr);
    f32x4 xn1 = *(const f32x4*)(xptr + 4);
    f16x8 xfrag = cvt8(xn0, xn1);

    #pragma unroll 1
    for (int s = 0; s < T_STEPS - 1; ++s) {
        const float dt = (s == 0) ? (t1v - t0v) : (ts[s - 1] - ts[s]);

        // ---- slot 1: prefetch next x; G1; xacc3 (G3 x-partials) ----
        xptr += 32;
        if (s < T_STEPS - 2) {
            xn0 = *(const f32x4*)(xptr);
            xn1 = *(const f32x4*)(xptr + 4);
        }
        f32x4 xacc3[4];
        {
            f16x8 b0 = ldsA(sYb, 64, c16, (g4 << 3));
            f16x8 b1 = ldsA(sYb, 64, c16, 32 + (g4 << 3));
            #pragma unroll
            for (int t = 0; t < 2; ++t) {
                int nt = wq + 4 * t;
                if (nt < 7) {
                    f32x4 acc0 = bo1v[t];
                    f32x4 z4 = {0.f, 0.f, 0.f, 0.f};
                    acc0 = MFMA16(Wv[(nt * 2 + 0) * 64 + lane], b0, acc0);
                    f32x4 acc1 = MFMA16(Wv[(nt * 2 + 1) * 64 + lane], b1, z4);
                    int ft = nt * 16 + (g4 << 2);
                    st4(sH1, 128, c16, ft,
                        fast_tanh(acc0[0] + acc1[0]), fast_tanh(acc0[1] + acc1[1]),
                        fast_tanh(acc0[2] + acc1[2]), fast_tanh(acc0[3] + acc1[3]));
                }
            }
            #pragma unroll
            for (int q = 0; q < 4; ++q) {
                int i = wq + 4 * q;
                if (i < 14) {
                    int bt = (i < 7) ? i : i + 1;
                    xacc3[q] = MFMA16(Wv[(14 + bt * 3 + 2) * 64 + lane], xfrag, bzrv[q]);
                }
            }
        }
        __syncthreads();

        // ---- slot 2: G2 (yode) + xacc5 (G5 x-partials) ----
        f32x4 xacc5[2];
        {
            f32x4 acc0 = bo2v;
            f32x4 z4 = {0.f, 0.f, 0.f, 0.f};
            acc0 = MFMA16(Ao2[0], ldsA(sH1, 128, c16, 0 * 32 + (g4 << 3)), acc0);
            f32x4 acc1 = MFMA16(Ao2[1], ldsA(sH1, 128, c16, 1 * 32 + (g4 << 3)), z4);
            acc0 = MFMA16(Ao2[2], ldsA(sH1, 128, c16, 2 * 32 + (g4 << 3)), acc0);
            acc1 = MFMA16(Ao2[3], ldsA(sH1, 128, c16, 3 * 32 + (g4 << 3)), acc1);
            #pragma unroll
            for (int t = 0; t < 2; ++t) {
                int nt = wq + 4 * t;
                if (nt < 7)
                    xacc5[t] = MFMA16(Wv[(91 + nt * 3 + 2) * 64 + lane], xfrag, bh1v[t]);
            }
            #pragma unroll
            for (int r = 0; r < 4; ++r) yo[r] = y[r] + dt * (acc0[r] + acc1[r]);
            st4(sYX, 64, c16, f0, yo[0], yo[1], yo[2], yo[3]);
        }
        __syncthreads();

        // ---- slot 3: G3 (2 MFMAs/tile, C-init = x-partial) ----
        {
            f16x8 b0 = ldsA(sYX, 64, c16, (g4 << 3));
            f16x8 b1 = ldsA(sYX, 64, c16, 32 + (g4 << 3));
            #pragma unroll
            for (int q = 0; q < 4; ++q) {
                int i = wq + 4 * q;
                if (i < 14) {
                    int bt = (i < 7) ? i : i + 1;
                    f32x4 acc = MFMA16(Wv[(14 + bt * 3 + 0) * 64 + lane], b0, xacc3[q]);
                    acc = MFMA16(Wv[(14 + bt * 3 + 1) * 64 + lane], b1, acc);
                    int ft = bt * 16 + (g4 << 2);
                    st4(sZR, 256, c16, ft,
                        fast_tanh(acc[0]), fast_tanh(acc[1]),
                        fast_tanh(acc[2]), fast_tanh(acc[3]));
                }
            }
        }
        __syncthreads();

        // ---- slot 4: G4 (z-gate -> regs ; r-gate*yode -> sRX) ----
        {
            f32x4 accz0 = bz2v, accr0 = br2v;
            f32x4 z4 = {0.f, 0.f, 0.f, 0.f};
            f32x4 accz1 = z4, accr1 = z4;
            accz0 = MFMA16(Wv[(59 + wq * 4 + 0) * 64 + lane], ldsA(sZR, 256, c16, 0 * 32 + (g4 << 3)), accz0);
            accr0 = MFMA16(Wv[(75 + wq * 4 + 0) * 64 + lane], ldsA(sZR, 256, c16, 128 + 0 * 32 + (g4 << 3)), accr0);
            accz1 = MFMA16(Wv[(59 + wq * 4 + 1) * 64 + lane], ldsA(sZR, 256, c16, 1 * 32 + (g4 << 3)), accz1);
            accr1 = MFMA16(Wv[(75 + wq * 4 + 1) * 64 + lane], ldsA(sZR, 256, c16, 128 + 1 * 32 + (g4 << 3)), accr1);
            accz0 = MFMA16(Wv[(59 + wq * 4 + 2) * 64 + lane], ldsA(sZR, 256, c16, 2 * 32 + (g4 << 3)), accz0);
            accr0 = MFMA16(Wv[(75 + wq * 4 + 2) * 64 + lane], ldsA(sZR, 256, c16, 128 + 2 * 32 + (g4 << 3)), accr0);
            accz1 = MFMA16(Wv[(59 + wq * 4 + 3) * 64 + lane], ldsA(sZR, 256, c16, 3 * 32 + (g4 << 3)), accz1);
            accr1 = MFMA16(Wv[(75 + wq * 4 + 3) * 64 + lane], ldsA(sZR, 256, c16, 128 + 3 * 32 + (g4 << 3)), accr1);
            float rv[4];
            #pragma unroll
            for (int r = 0; r < 4; ++r) {
                zg[r] = fast_sigmoid(accz0[r] + accz1[r]);
                rv[r] = fast_sigmoid(accr0[r] + accr1[r]) * yo[r];
            }
            st4(sRX, 64, c16, f0, rv[0], rv[1], rv[2], rv[3]);
        }
        __syncthreads();

        // ---- slot 5: G5 (2 MFMAs/tile, C-init = x-partial) ----
        {
            f16x8 b0 = ldsA(sRX, 64, c16, (g4 << 3));
            f16x8 b1 = ldsA(sRX, 64, c16, 32 + (g4 << 3));
            #pragma unroll
            for (int t = 0; t < 2; ++t) {
                int nt = wq + 4 * t;
                if (nt < 7) {
                    f32x4 acc = MFMA16(Wv[(91 + nt * 3 + 0) * 64 + lane], b0, xacc5[t]);
                    acc = MFMA16(Wv[(91 + nt * 3 + 1) * 64 + lane], b1, acc);
                    int ft = nt * 16 + (g4 << 2);
                    st4(sH1, 128, c16, ft,
                        fast_tanh(acc[0]), fast_tanh(acc[1]),
                        fast_tanh(acc[2]), fast_tanh(acc[3]));
                }
            }
        }
        __syncthreads();

        // ---- slot 6: G6 (h, blend, y) ----
        {
            f32x4 acc0 = bh2v;
            f32x4 z4 = {0.f, 0.f, 0.f, 0.f};
            acc0 = MFMA16(Ah2[0], ldsA(sH1, 128, c16, 0 * 32 + (g4 << 3)), acc0);
            f32x4 acc1 = MFMA16(Ah2[1], ldsA(sH1, 128, c16, 1 * 32 + (g4 << 3)), z4);
            acc0 = MFMA16(Ah2[2], ldsA(sH1, 128, c16, 2 * 32 + (g4 << 3)), acc0);
            acc1 = MFMA16(Ah2[3], ldsA(sH1, 128, c16, 3 * 32 + (g4 << 3)), acc1);
            #pragma unroll
            for (int r = 0; r < 4; ++r) {
                float h = fast_tanh(acc0[r] + acc1[r]);
                y[r] = (1.f - zg[r]) * h + zg[r] * yo[r];
            }
            st4(sYb, 64, c16, f0, y[0], y[1], y[2], y[3]);
        }
        __syncthreads();

        xfrag = cvt8(xn0, xn1);   // pack prefetched x for next step
    }

    {
        f32x4 ov = {y[0], y[1], y[2], y[3]};
        *(f32x4*)(out + (size_t)(m0 + c16) * 64 + f0) = ov;
    }
}

extern "C" void kernel_launch(void* const* d_in, const int* in_sizes, int n_in,
                              void* d_out, int out_size, void* d_ws, size_t ws_size,
                              hipStream_t stream) {
    const float* data = (const float*)d_in[0];
    const float* ts   = (const float*)d_in[1];
    const float* prior= (const float*)d_in[2];
    const float* Wo1 = (const float*)d_in[3];  const float* bo1 = (const float*)d_in[4];
    const float* Wo2 = (const float*)d_in[5];  const float* bo2 = (const float*)d_in[6];
    const float* Wz1 = (const float*)d_in[7];  const float* bz1 = (const float*)d_in[8];
    const float* Wz2 = (const float*)d_in[9];  const float* bz2 = (const float*)d_in[10];
    const float* Wr1 = (const float*)d_in[11]; const float* br1 = (const float*)d_in[12];
    const float* Wr2 = (const float*)d_in[13]; const float* br2 = (const float*)d_in[14];
    const float* Wh1 = (const float*)d_in[15]; const float* bh1 = (const float*)d_in[16];
    const float* Wh2 = (const float*)d_in[17]; const float* bh2 = (const float*)d_in[18];
    _Float16* P = (_Float16*)d_ws;
    float* out = (float*)d_out;

    (void)hipFuncSetAttribute((const void*)odernn_kernel,
                              hipFuncAttributeMaxDynamicSharedMemorySize, LDS_TOTAL);

    hipLaunchKernelGGL(pack_kernel, dim3((144 * 512 + 255) / 256), dim3(256), 0, stream,
                       Wo1, Wo2, Wz1, Wz2, Wr1, Wr2, Wh1, Wh2, P);
    hipLaunchKernelGGL(odernn_kernel, dim3(NTRAJ / MBLK), dim3(512), LDS_TOTAL, stream,
                       data, ts, prior, bo1, bo2, bz1, bz2, br1, br2, bh1, bh2, P, out);
}